// Round 1
// baseline (1225.400 us; speedup 1.0000x reference)
//
#include <hip/hip_runtime.h>

#define N_NODES 200000
#define N_EDGES 6400000
#define IN_FEAT 128
#define HIDDEN  16

// ---------------- degree / norm ----------------

__global__ void k_init_deg(float* __restrict__ deg) {
    int i = blockIdx.x * blockDim.x + threadIdx.x;
    if (i < N_NODES) deg[i] = 1.0f;   // self-loop contributes 1
}

__global__ void k_accum_deg(const int* __restrict__ col, float* __restrict__ deg) {
    int e = blockIdx.x * blockDim.x + threadIdx.x;
    if (e < N_EDGES) unsafeAtomicAdd(&deg[col[e]], 1.0f);
}

__global__ void k_finalize_dinv(float* __restrict__ deg) {
    int i = blockIdx.x * blockDim.x + threadIdx.x;
    if (i < N_NODES) deg[i] = rsqrtf(deg[i]);   // deg >= 1 always (self-loops)
}

// ---------------- layer-1 GEMM: h = x @ W1  (200000x128 @ 128x16) ----------------
// Block = 256 threads handles 16 node rows. x tile staged in LDS (stride 132 to
// avoid 4-way bank conflicts at stride 128), W1 staged in LDS (broadcast reads).

__global__ __launch_bounds__(256) void k_gemm1(const float* __restrict__ x,
                                               const float* __restrict__ W1,
                                               float* __restrict__ h) {
    __shared__ float xs[16][132];
    __shared__ float ws[IN_FEAT * HIDDEN];   // 8 KB

    const int tid = threadIdx.x;
    const int block_node = blockIdx.x * 16;

    for (int i = tid; i < IN_FEAT * HIDDEN; i += 256) ws[i] = W1[i];

    const int rows = min(16, N_NODES - block_node);
    const float4* x4 = (const float4*)(x + (size_t)block_node * IN_FEAT);
    // rows*32 float4 loads, fully coalesced (16 consecutive rows are contiguous)
    for (int i = tid; i < rows * 32; i += 256) {
        float4 v = x4[i];
        int r = i >> 5, c = (i & 31) << 2;
        *(float4*)&xs[r][c] = v;
    }
    __syncthreads();

    const int n = tid >> 4, f = tid & 15;
    if (block_node + n < N_NODES) {
        float acc = 0.f;
        #pragma unroll 8
        for (int k = 0; k < IN_FEAT; ++k)
            acc = fmaf(xs[n][k], ws[k * HIDDEN + f], acc);
        h[(size_t)(block_node + n) * HIDDEN + f] = acc;
    }
}

// ---------------- layer-1 edge scatter ----------------
// One thread per (edge, feature): 16 consecutive lanes handle one edge, so the
// h[row] gather and the agg[col] atomics are each 64B-contiguous per edge.
// Edge ids [N_EDGES, N_EDGES+N_NODES) are the self-loops.

__global__ void k_scatter1(const int* __restrict__ row, const int* __restrict__ col,
                           const float* __restrict__ dinv, const float* __restrict__ h,
                           float* __restrict__ agg) {
    long long tid = (long long)blockIdx.x * blockDim.x + threadIdx.x;
    long long e = tid >> 4;
    int f = (int)(tid & 15);
    if (e >= (long long)(N_EDGES + N_NODES)) return;
    int r, c; float norm;
    if (e < N_EDGES) {
        r = row[e]; c = col[e];
        norm = dinv[r] * dinv[c];
    } else {
        r = c = (int)(e - N_EDGES);
        float d = dinv[r]; norm = d * d;
    }
    unsafeAtomicAdd(&agg[(size_t)c * HIDDEN + f], norm * h[(size_t)r * HIDDEN + f]);
}

// ---------------- fused bias + relu + layer-2 GEMV: t = relu(agg + b1) @ W2 ----------------

__global__ void k_node2(const float* __restrict__ agg, const float* __restrict__ b1,
                        const float* __restrict__ W2, float* __restrict__ t) {
    int i = blockIdx.x * blockDim.x + threadIdx.x;
    if (i >= N_NODES) return;
    const float4* a4 = (const float4*)(agg + (size_t)i * HIDDEN);
    float acc = 0.f;
    #pragma unroll
    for (int q = 0; q < 4; ++q) {
        float4 v = a4[q];
        acc = fmaf(fmaxf(v.x + b1[4*q+0], 0.f), W2[4*q+0], acc);
        acc = fmaf(fmaxf(v.y + b1[4*q+1], 0.f), W2[4*q+1], acc);
        acc = fmaf(fmaxf(v.z + b1[4*q+2], 0.f), W2[4*q+2], acc);
        acc = fmaf(fmaxf(v.w + b1[4*q+3], 0.f), W2[4*q+3], acc);
    }
    t[i] = acc;
}

// ---------------- layer-2 output ----------------

__global__ void k_init_out(float* __restrict__ out, const float* __restrict__ b2) {
    int i = blockIdx.x * blockDim.x + threadIdx.x;
    if (i < N_NODES) out[i] = b2[0];
}

__global__ void k_scatter2(const int* __restrict__ row, const int* __restrict__ col,
                           const float* __restrict__ dinv, const float* __restrict__ t,
                           float* __restrict__ out) {
    long long e = (long long)blockIdx.x * blockDim.x + threadIdx.x;
    if (e >= (long long)(N_EDGES + N_NODES)) return;
    int r, c; float norm;
    if (e < N_EDGES) {
        r = row[e]; c = col[e];
        norm = dinv[r] * dinv[c];
    } else {
        r = c = (int)(e - N_EDGES);
        float d = dinv[r]; norm = d * d;
    }
    unsafeAtomicAdd(&out[c], norm * t[r]);
}

// ---------------- launch ----------------

extern "C" void kernel_launch(void* const* d_in, const int* in_sizes, int n_in,
                              void* d_out, int out_size, void* d_ws, size_t ws_size,
                              hipStream_t stream) {
    const float* x   = (const float*)d_in[0];
    const int*   ei  = (const int*)d_in[1];       // [2, N_EDGES]
    const float* W1  = (const float*)d_in[2];
    const float* b1  = (const float*)d_in[3];
    const float* W2  = (const float*)d_in[4];
    const float* b2  = (const float*)d_in[5];
    float* out = (float*)d_out;

    const int* row = ei;               // sources
    const int* col = ei + N_EDGES;     // targets

    // workspace layout (floats): dinv[N] | h[16N] | agg[16N] | t[N]  = 34N floats
    float* dinv = (float*)d_ws;
    float* h    = dinv + N_NODES;
    float* agg  = h + (size_t)N_NODES * HIDDEN;
    float* t    = agg + (size_t)N_NODES * HIDDEN;

    const int B = 256;
    const int gN = (N_NODES + B - 1) / B;
    const int gE = (N_EDGES + B - 1) / B;
    const long long EL = (long long)N_EDGES + N_NODES;
    const int gEL  = (int)((EL + B - 1) / B);
    const int gEL16 = (int)((EL * 16 + B - 1) / B);

    k_init_deg<<<gN, B, 0, stream>>>(dinv);
    hipMemsetAsync(agg, 0, (size_t)N_NODES * HIDDEN * sizeof(float), stream);
    k_accum_deg<<<gE, B, 0, stream>>>(col, dinv);
    k_finalize_dinv<<<gN, B, 0, stream>>>(dinv);

    k_gemm1<<<(N_NODES + 15) / 16, B, 0, stream>>>(x, W1, h);
    k_scatter1<<<gEL16, B, 0, stream>>>(row, col, dinv, h, agg);

    k_node2<<<gN, B, 0, stream>>>(agg, b1, W2, t);
    k_init_out<<<gN, B, 0, stream>>>(out, b2);
    k_scatter2<<<gEL, B, 0, stream>>>(row, col, dinv, t, out);
}

// Round 2
// 1189.522 us; speedup vs baseline: 1.0302x; 1.0302x over previous
//
#include <hip/hip_runtime.h>

#define N_NODES 200000
#define N_EDGES 6400000
#define IN_FEAT 128
#define HIDDEN  16
#define SCAN_B  256
#define NB_SCAN ((N_NODES + SCAN_B - 1) / SCAN_B)   // 782 partial blocks

// ---------------- degree count (u32 atomics) ----------------

__global__ void k_count(const int* __restrict__ col, unsigned* __restrict__ cnt) {
    int e = blockIdx.x * blockDim.x + threadIdx.x;
    if (e < N_EDGES) atomicAdd(&cnt[col[e]], 1u);
}

__global__ void k_dinv(const unsigned* __restrict__ cnt, float* __restrict__ dinv) {
    int i = blockIdx.x * blockDim.x + threadIdx.x;
    if (i < N_NODES) dinv[i] = rsqrtf((float)cnt[i] + 1.0f);   // +1 self-loop
}

// ---------------- 2-level exclusive scan of cnt -> off ----------------

__global__ void k_scan1(const unsigned* __restrict__ cnt, unsigned* __restrict__ off,
                        unsigned* __restrict__ part) {
    __shared__ unsigned s[SCAN_B];
    int i = blockIdx.x * SCAN_B + threadIdx.x;
    unsigned v = (i < N_NODES) ? cnt[i] : 0u;
    s[threadIdx.x] = v;
    __syncthreads();
    for (int d = 1; d < SCAN_B; d <<= 1) {
        unsigned t = (threadIdx.x >= d) ? s[threadIdx.x - d] : 0u;
        __syncthreads();
        s[threadIdx.x] += t;
        __syncthreads();
    }
    if (i < N_NODES) off[i] = s[threadIdx.x] - v;          // exclusive within block
    if (threadIdx.x == SCAN_B - 1) part[blockIdx.x] = s[threadIdx.x];
}

__global__ void k_scan2(unsigned* __restrict__ part) {
    __shared__ unsigned s[SCAN_B];
    __shared__ unsigned carry;
    if (threadIdx.x == 0) carry = 0u;
    __syncthreads();
    for (int base = 0; base < NB_SCAN; base += SCAN_B) {
        int i = base + threadIdx.x;
        unsigned v = (i < NB_SCAN) ? part[i] : 0u;
        s[threadIdx.x] = v;
        __syncthreads();
        for (int d = 1; d < SCAN_B; d <<= 1) {
            unsigned t = (threadIdx.x >= d) ? s[threadIdx.x - d] : 0u;
            __syncthreads();
            s[threadIdx.x] += t;
            __syncthreads();
        }
        if (i < NB_SCAN) part[i] = s[threadIdx.x] - v + carry;   // exclusive + carry
        __syncthreads();
        if (threadIdx.x == 0) carry += s[SCAN_B - 1];
        __syncthreads();
    }
}

__global__ void k_scan3(unsigned* __restrict__ off, const unsigned* __restrict__ part) {
    int i = blockIdx.x * blockDim.x + threadIdx.x;
    if (i < N_NODES) off[i] += part[i >> 8];
}

// ---------------- CSR fill: off doubles as cursor ----------------
// After this kernel off[c] == original off[c+1] (each advanced by its count).

__global__ void k_fill(const int* __restrict__ row, const int* __restrict__ col,
                       unsigned* __restrict__ off, unsigned* __restrict__ csr) {
    int e = blockIdx.x * blockDim.x + threadIdx.x;
    if (e >= N_EDGES) return;
    int c = col[e];
    unsigned slot = atomicAdd(&off[c], 1u);
    csr[slot] = (unsigned)row[e];
}

// ---------------- layer-1 GEMM: h = x @ W1 ----------------

__global__ __launch_bounds__(256) void k_gemm1(const float* __restrict__ x,
                                               const float* __restrict__ W1,
                                               float* __restrict__ h) {
    __shared__ float xs[16][132];
    __shared__ float ws[IN_FEAT * HIDDEN];

    const int tid = threadIdx.x;
    const int block_node = blockIdx.x * 16;

    for (int i = tid; i < IN_FEAT * HIDDEN; i += 256) ws[i] = W1[i];

    const int rows = min(16, N_NODES - block_node);
    const float4* x4 = (const float4*)(x + (size_t)block_node * IN_FEAT);
    for (int i = tid; i < rows * 32; i += 256) {
        float4 v = x4[i];
        int r = i >> 5, c = (i & 31) << 2;
        *(float4*)&xs[r][c] = v;
    }
    __syncthreads();

    const int n = tid >> 4, f = tid & 15;
    if (block_node + n < N_NODES) {
        float acc = 0.f;
        #pragma unroll 8
        for (int k = 0; k < IN_FEAT; ++k)
            acc = fmaf(xs[n][k], ws[k * HIDDEN + f], acc);
        h[(size_t)(block_node + n) * HIDDEN + f] = acc;
    }
}

// ---------------- gather layer 1 (fused bias+relu+W2 -> t) ----------------
// 16 lanes per node: lane f owns feature f. csr/dinv reads are 16-lane
// broadcasts; h gathers are 64B-contiguous per edge. No atomics.

__global__ __launch_bounds__(256) void k_gather1(const unsigned* __restrict__ csr,
                                                 const unsigned* __restrict__ offA,
                                                 const float* __restrict__ dinv,
                                                 const float* __restrict__ h,
                                                 const float* __restrict__ b1,
                                                 const float* __restrict__ W2,
                                                 float* __restrict__ t) {
    int tid = blockIdx.x * blockDim.x + threadIdx.x;
    int i = tid >> 4, f = tid & 15;
    if (i >= N_NODES) return;
    unsigned end = offA[i];
    unsigned k = (i == 0) ? 0u : offA[i - 1];
    float di = dinv[i];
    float acc = di * h[(size_t)i * HIDDEN + f];      // self-loop (norm di*di, di applied below)
    float edge_acc = 0.f;
    for (; k + 1 < end; k += 2) {                    // 2-wide for outstanding loads
        unsigned s0 = csr[k], s1 = csr[k + 1];
        float n0 = dinv[s0], n1 = dinv[s1];
        float h0 = h[(size_t)s0 * HIDDEN + f], h1 = h[(size_t)s1 * HIDDEN + f];
        edge_acc = fmaf(n0, h0, edge_acc);
        edge_acc = fmaf(n1, h1, edge_acc);
    }
    if (k < end) {
        unsigned s0 = csr[k];
        edge_acc = fmaf(dinv[s0], h[(size_t)s0 * HIDDEN + f], edge_acc);
    }
    acc = di * (acc + edge_acc);                     // norm = di * dinv[src] (self: di*di)
    float r = fmaxf(acc + b1[f], 0.f) * W2[f];
    r += __shfl_xor(r, 8, 16);
    r += __shfl_xor(r, 4, 16);
    r += __shfl_xor(r, 2, 16);
    r += __shfl_xor(r, 1, 16);
    if (f == 0) t[i] = r;
}

// ---------------- gather layer 2 -> out ----------------
// 16 lanes per node stride the edge list (coalesced csr reads); t/dinv gathers
// are scalar within 800KB L2-resident arrays.

__global__ __launch_bounds__(256) void k_gather2(const unsigned* __restrict__ csr,
                                                 const unsigned* __restrict__ offA,
                                                 const float* __restrict__ dinv,
                                                 const float* __restrict__ t,
                                                 const float* __restrict__ b2,
                                                 float* __restrict__ out) {
    int tid = blockIdx.x * blockDim.x + threadIdx.x;
    int i = tid >> 4, l = tid & 15;
    if (i >= N_NODES) return;
    unsigned end = offA[i];
    unsigned start = (i == 0) ? 0u : offA[i - 1];
    float acc = 0.f;
    for (unsigned k = start + l; k < end; k += 16) {
        unsigned s = csr[k];
        acc = fmaf(dinv[s], t[s], acc);
    }
    acc += __shfl_xor(acc, 8, 16);
    acc += __shfl_xor(acc, 4, 16);
    acc += __shfl_xor(acc, 2, 16);
    acc += __shfl_xor(acc, 1, 16);
    if (l == 0) {
        float di = dinv[i];
        out[i] = fmaf(di, acc, fmaf(di * di, t[i], b2[0]));
    }
}

// ---------------- launch ----------------

extern "C" void kernel_launch(void* const* d_in, const int* in_sizes, int n_in,
                              void* d_out, int out_size, void* d_ws, size_t ws_size,
                              hipStream_t stream) {
    const float* x   = (const float*)d_in[0];
    const int*   ei  = (const int*)d_in[1];
    const float* W1  = (const float*)d_in[2];
    const float* b1  = (const float*)d_in[3];
    const float* W2  = (const float*)d_in[4];
    const float* b2  = (const float*)d_in[5];
    float* out = (float*)d_out;

    const int* row = ei;               // sources
    const int* col = ei + N_EDGES;     // targets

    // workspace layout:
    // cnt u32[N] | off u32[N] | part u32[1024] | dinv f32[N] | csr u32[E] | h f32[16N] | t f32[N]
    unsigned* cnt  = (unsigned*)d_ws;
    unsigned* off  = cnt + N_NODES;
    unsigned* part = off + N_NODES;
    float*    dinv = (float*)(part + 1024);
    unsigned* csr  = (unsigned*)(dinv + N_NODES);
    float*    h    = (float*)(csr + N_EDGES);
    float*    t    = h + (size_t)N_NODES * HIDDEN;

    const int B = 256;
    const int gN   = (N_NODES + B - 1) / B;
    const int gE   = (N_EDGES + B - 1) / B;
    const int gN16 = (N_NODES * 16 + B - 1) / B;

    hipMemsetAsync(cnt, 0, N_NODES * sizeof(unsigned), stream);
    k_count<<<gE, B, 0, stream>>>(col, cnt);
    k_dinv<<<gN, B, 0, stream>>>(cnt, dinv);
    k_scan1<<<NB_SCAN, SCAN_B, 0, stream>>>(cnt, off, part);
    k_scan2<<<1, SCAN_B, 0, stream>>>(part);
    k_scan3<<<gN, B, 0, stream>>>(off, part);
    k_fill<<<gE, B, 0, stream>>>(row, col, off, csr);   // off -> shifted offsets

    k_gemm1<<<(N_NODES + 15) / 16, B, 0, stream>>>(x, W1, h);
    k_gather1<<<gN16, B, 0, stream>>>(csr, off, dinv, h, b1, W2, t);
    k_gather2<<<gN16, B, 0, stream>>>(csr, off, dinv, t, b2, out);
}